// Round 10
// baseline (843.935 us; speedup 1.0000x reference)
//
#include <hip/hip_runtime.h>
#include <cstddef>

#define SLOPE_F (11.0f / 48.0f)

static const int NN = 50000;     // nodes
static const int EE = 1600000;   // edges per timestep
static const int D  = 256;
static const int NCH = 196;      // scan chunks = ceil(NN/256)
static const int GB  = 391;      // gemm blocks = ceil(NN/128)

typedef __attribute__((ext_vector_type(8))) short short8;
typedef __attribute__((ext_vector_type(4))) float f32x4;

__device__ __forceinline__ ushort f2bf(float f) {
    unsigned u = __float_as_uint(f);
    unsigned r = (u + 0x7fffu + ((u >> 16) & 1u)) >> 16;
    return (ushort)r;
}
__device__ __forceinline__ float bf2f(ushort u) {
    return __uint_as_float(((unsigned)u) << 16);
}

// ---------------- prep + dst histogram ----------------
// blocks [0,64): GRU weights -> WB[mat][hi/lo][i][k] bf16 (mat = layer*4 + {z,r,h,u})
// blocks [64,80): BtW1[n][k] = bf16(W1[k][n])
// blocks [80,112): Qt[layer][j][i] = bf16(Q0[i][j])
// blocks [112, ...): histogram of dst into deg
__global__ __launch_bounds__(256) void prephist_kernel(
        const float* __restrict__ Wz0, const float* __restrict__ Uz0,
        const float* __restrict__ Wr0, const float* __restrict__ Ur0,
        const float* __restrict__ Wh0, const float* __restrict__ Uh0,
        const float* __restrict__ Wz1, const float* __restrict__ Uz1,
        const float* __restrict__ Wr1, const float* __restrict__ Ur1,
        const float* __restrict__ Wh1, const float* __restrict__ Uh1,
        const float* __restrict__ W1,
        const float* __restrict__ Q00, const float* __restrict__ Q01,
        ushort* __restrict__ WB, ushort* __restrict__ BtW1, ushort* __restrict__ Qt,
        const int* __restrict__ dst, int* __restrict__ deg) {
    int b = blockIdx.x;
    int tid = threadIdx.x;
    if (b >= 112) {
        int e = (b - 112) * 256 + tid;
        if (e < EE) atomicAdd(&deg[dst[e]], 1);
        return;
    }
    if (b < 64) {
        int mat = b >> 3;
        const float* P = nullptr; const float* S = nullptr;
        switch (mat) {
            case 0: P = Wz0; S = Uz0; break;
            case 1: P = Wr0; S = Ur0; break;
            case 2: P = Wh0; break;
            case 3: P = Uh0; break;
            case 4: P = Wz1; S = Uz1; break;
            case 5: P = Wr1; S = Ur1; break;
            case 6: P = Wh1; break;
            default: P = Uh1; break;
        }
        size_t base = (size_t)mat * 2 * 65536;
#pragma unroll 4
        for (int u = 0; u < 32; ++u) {
            int idx = (b & 7) * 8192 + u * 256 + tid;
            float v = P[idx];
            if (S) v += S[idx];
            ushort hi = f2bf(v);
            ushort lo = f2bf(v - bf2f(hi));
            WB[base + idx] = hi;
            WB[base + 65536 + idx] = lo;
        }
        return;
    }
    __shared__ float lt[64][65];
    if (b < 80) {
        int t = b - 64;
        int tr = (t >> 2) & 3, tc = t & 3;
#pragma unroll
        for (int r0 = 0; r0 < 64; r0 += 4) {
            int r = r0 + (tid >> 6);
            int c = tid & 63;
            lt[r][c] = W1[(tr * 64 + r) * 256 + tc * 64 + c];
        }
        __syncthreads();
#pragma unroll
        for (int c0 = 0; c0 < 64; c0 += 4) {
            int c = c0 + (tid >> 6);
            int r = tid & 63;
            BtW1[(size_t)(tc * 64 + c) * 256 + tr * 64 + r] = f2bf(lt[r][c]);
        }
    } else {
        int t = b - 80;             // 0..31
        int layer = t >> 4;
        int tt = t & 15;
        int tr = (tt >> 2) & 3, tc = tt & 3;
        const float* Q0 = layer ? Q01 : Q00;
#pragma unroll
        for (int r0 = 0; r0 < 64; r0 += 4) {
            int r = r0 + (tid >> 6);
            int c = tid & 63;
            lt[r][c] = Q0[(tr * 64 + r) * 256 + tc * 64 + c];
        }
        __syncthreads();
#pragma unroll
        for (int c0 = 0; c0 < 64; c0 += 4) {
            int c = c0 + (tid >> 6);
            int r = tid & 63;
            Qt[(size_t)layer * 65536 + (size_t)(tc * 64 + c) * 256 + tr * 64 + r] =
                f2bf(lt[r][c]);
        }
    }
}

// ---------------- grid barrier (device-scope, distinct counter per use) ----------------
__device__ __forceinline__ void gridbar(int* __restrict__ bar, int idx, int nb) {
    __threadfence();
    __syncthreads();
    if (threadIdx.x == 0) {
        atomicAdd(&bar[idx], 1);
        while (atomicAdd(&bar[idx], 0) < nb) { __builtin_amdgcn_s_sleep(8); }
        __threadfence();
    }
    __syncthreads();
}

// ---------------- MFMA GRU (blocks 0-127) + chunk-scan (blocks 128..323) ----------------
// One 16x16 output tile per wave; 512 waves cover 2 layers x 256 tiles.
// Qt[layer][j][i] bf16 doubles as the final GEMM B-matrix (Bt layout).
__global__ __launch_bounds__(256, 2) void grubar_kernel(
        const ushort* __restrict__ WB,
        const float* __restrict__ bz0, const float* __restrict__ br0,
        const float* __restrict__ bh0,
        const float* __restrict__ bz1, const float* __restrict__ br1,
        const float* __restrict__ bh1,
        ushort* __restrict__ Qt, ushort* __restrict__ RQt, int* __restrict__ bar,
        const int* __restrict__ deg, int* __restrict__ rs, int* __restrict__ cur,
        int* __restrict__ bsum, int* __restrict__ boff, int* __restrict__ done) {
    int tid = threadIdx.x;
    if (blockIdx.x >= 128) {
        // ---- chunk-local exclusive scan + last-block finisher ----
        __shared__ int wsum[4];
        __shared__ int lastflag;
        int blk = blockIdx.x - 128;          // 0..195
        int i = blk * 256 + tid;
        int lane = tid & 63, wv = tid >> 6;
        int v = (i < NN) ? deg[i] : 0;
        int x = v;
#pragma unroll
        for (int off = 1; off < 64; off <<= 1) {
            int t = __shfl_up(x, off, 64);
            if (lane >= off) x += t;
        }
        if (lane == 63) wsum[wv] = x;
        __syncthreads();
        if (tid == 0) {
            int s = 0;
#pragma unroll
            for (int q = 0; q < 4; ++q) { int t = wsum[q]; wsum[q] = s; s += t; }
            bsum[blk] = s;
        }
        __syncthreads();
        if (i < NN) { int p = wsum[wv] + x - v; rs[i] = p; cur[i] = p; }
        __threadfence();
        if (tid == 0) lastflag = (atomicAdd(done, 1) == NCH - 1);
        __syncthreads();
        if (lastflag) {
            __threadfence();
            int bv = (tid < NCH) ? bsum[tid] : 0;
            int bx = bv;
#pragma unroll
            for (int off = 1; off < 64; off <<= 1) {
                int t = __shfl_up(bx, off, 64);
                if (lane >= off) bx += t;
            }
            if (lane == 63) wsum[wv] = bx;
            __syncthreads();
            if (tid == 0) {
                int s = 0;
#pragma unroll
                for (int q = 0; q < 4; ++q) { int t = wsum[q]; wsum[q] = s; s += t; }
            }
            __syncthreads();
            if (tid < NCH) boff[tid] = wsum[wv] + bx - bv;
        }
        return;
    }
    // ---- MFMA GRU ----
    int wid = blockIdx.x * 4 + (tid >> 6);   // 0..511
    int l = tid & 63;
    int layer = wid >> 8;
    int t = wid & 255;
    int i0 = (t >> 4) * 16;
    int j0 = (t & 15) * 16;
    int lr = l & 15, lk = l >> 4;
    int ro = lk * 4;

    const ushort* Wz = WB + ((size_t)layer * 4 + 0) * 2 * 65536;
    const ushort* Wr = WB + ((size_t)layer * 4 + 1) * 2 * 65536;
    const ushort* Wh = WB + ((size_t)layer * 4 + 2) * 2 * 65536;
    const ushort* Wu = WB + ((size_t)layer * 4 + 3) * 2 * 65536;
    ushort* Qtl  = Qt  + (size_t)layer * 65536;
    ushort* RQtl = RQt + (size_t)layer * 65536;
    const float* bz = layer ? bz1 : bz0;
    const float* br = layer ? br1 : br0;
    const float* bh = layer ? bh1 : bh0;

    float bza[4], bra[4], bha[4];
#pragma unroll
    for (int q = 0; q < 4; ++q) {
        int i = i0 + ro + q;
        bza[q] = bz[i * 256 + j0 + lr];
        bra[q] = br[i * 256 + j0 + lr];
        bha[q] = bh[i * 256 + j0 + lr];
    }

    const int afo = (i0 + lr) * 256 + lk * 8;   // A-frag base (weight rows i)
    const int bfo = (j0 + lr) * 256 + lk * 8;   // B-frag base (Qt/RQt rows j)
    const int qo  = (j0 + lr) * 256 + i0 + ro;  // per-lane Q element base

    for (int step = 0; step < 6; ++step) {
        f32x4 az = {}, ar = {}, ah = {};
#pragma unroll
        for (int kc = 0; kc < 8; ++kc) {
            short8 qf  = *(const short8*)&Qtl[bfo + kc * 32];
            short8 wzh = *(const short8*)&Wz[afo + kc * 32];
            short8 wzl = *(const short8*)&Wz[65536 + afo + kc * 32];
            az = __builtin_amdgcn_mfma_f32_16x16x32_bf16(wzh, qf, az, 0, 0, 0);
            az = __builtin_amdgcn_mfma_f32_16x16x32_bf16(wzl, qf, az, 0, 0, 0);
            short8 wrh = *(const short8*)&Wr[afo + kc * 32];
            short8 wrl = *(const short8*)&Wr[65536 + afo + kc * 32];
            ar = __builtin_amdgcn_mfma_f32_16x16x32_bf16(wrh, qf, ar, 0, 0, 0);
            ar = __builtin_amdgcn_mfma_f32_16x16x32_bf16(wrl, qf, ar, 0, 0, 0);
            short8 whh = *(const short8*)&Wh[afo + kc * 32];
            short8 whl = *(const short8*)&Wh[65536 + afo + kc * 32];
            ah = __builtin_amdgcn_mfma_f32_16x16x32_bf16(whh, qf, ah, 0, 0, 0);
            ah = __builtin_amdgcn_mfma_f32_16x16x32_bf16(whl, qf, ah, 0, 0, 0);
        }
        ushort4 qv4 = *(const ushort4*)&Qtl[qo];
        float qv[4] = {bf2f(qv4.x), bf2f(qv4.y), bf2f(qv4.z), bf2f(qv4.w)};
        float zz[4];
        ushort4 rq4;
        {
            float rr0 = 1.f / (1.f + expf(-(ar[0] + bra[0])));
            float rr1 = 1.f / (1.f + expf(-(ar[1] + bra[1])));
            float rr2 = 1.f / (1.f + expf(-(ar[2] + bra[2])));
            float rr3 = 1.f / (1.f + expf(-(ar[3] + bra[3])));
            zz[0] = 1.f / (1.f + expf(-(az[0] + bza[0])));
            zz[1] = 1.f / (1.f + expf(-(az[1] + bza[1])));
            zz[2] = 1.f / (1.f + expf(-(az[2] + bza[2])));
            zz[3] = 1.f / (1.f + expf(-(az[3] + bza[3])));
            rq4.x = f2bf(rr0 * qv[0]);
            rq4.y = f2bf(rr1 * qv[1]);
            rq4.z = f2bf(rr2 * qv[2]);
            rq4.w = f2bf(rr3 * qv[3]);
        }
        *(ushort4*)&RQtl[qo] = rq4;
        gridbar(bar, step * 2, 128);

        f32x4 au = {};
#pragma unroll
        for (int kc = 0; kc < 8; ++kc) {
            short8 rf  = *(const short8*)&RQtl[bfo + kc * 32];
            short8 wuh = *(const short8*)&Wu[afo + kc * 32];
            short8 wul = *(const short8*)&Wu[65536 + afo + kc * 32];
            au = __builtin_amdgcn_mfma_f32_16x16x32_bf16(wuh, rf, au, 0, 0, 0);
            au = __builtin_amdgcn_mfma_f32_16x16x32_bf16(wul, rf, au, 0, 0, 0);
        }
        ushort4 qn4;
#pragma unroll
        for (int q = 0; q < 4; ++q) {
            float h = tanhf(ah[q] + au[q] + bha[q]);
            float qn = (1.f - zz[q]) * qv[q] + zz[q] * h;
            ((ushort*)&qn4)[q] = f2bf(qn);
        }
        *(ushort4*)&Qtl[qo] = qn4;
        if (step < 5) gridbar(bar, step * 2 + 1, 128);
    }
}

// ---------------- MFMA GEMM body (no LDS; B is L1/L2-resident) ----------------
template <int ASRC, int EPI>
__device__ __forceinline__ void gemm_body(int bid, int tid,
                                          const ushort* __restrict__ A,
                                          const float* __restrict__ Af,
                                          const ushort* __restrict__ Bt,
                                          const float* __restrict__ bias,
                                          ushort* __restrict__ C, int M) {
    int w = tid >> 6, l = tid & 63;
    int lr = l & 15;
    int lk = l >> 4;
    int row0 = bid * 128 + w * 32;
    int ra = row0 + lr;      if (ra > M - 1) ra = M - 1;
    int rb = row0 + 16 + lr; if (rb > M - 1) rb = M - 1;
    const ushort* Ap0  = A  + (size_t)ra * 256 + lk * 8;
    const ushort* Ap1  = A  + (size_t)rb * 256 + lk * 8;
    const float*  Apf0 = Af + (size_t)ra * 256 + lk * 8;
    const float*  Apf1 = Af + (size_t)rb * 256 + lk * 8;
    const ushort* Bp   = Bt + (size_t)lr * 256 + lk * 8;

    f32x4 acc0[16] = {};
    f32x4 acc1[16] = {};
#pragma unroll
    for (int kc = 0; kc < 8; ++kc) {
        short8 a0, a1;
        if (ASRC == 0) {
            a0 = *(const short8*)(Ap0 + kc * 32);
            a1 = *(const short8*)(Ap1 + kc * 32);
        } else {
            float4 f0 = *(const float4*)(Apf0 + kc * 32);
            float4 f1 = *(const float4*)(Apf0 + kc * 32 + 4);
            float4 g0 = *(const float4*)(Apf1 + kc * 32);
            float4 g1 = *(const float4*)(Apf1 + kc * 32 + 4);
            a0[0] = (short)f2bf(f0.x); a0[1] = (short)f2bf(f0.y);
            a0[2] = (short)f2bf(f0.z); a0[3] = (short)f2bf(f0.w);
            a0[4] = (short)f2bf(f1.x); a0[5] = (short)f2bf(f1.y);
            a0[6] = (short)f2bf(f1.z); a0[7] = (short)f2bf(f1.w);
            a1[0] = (short)f2bf(g0.x); a1[1] = (short)f2bf(g0.y);
            a1[2] = (short)f2bf(g0.z); a1[3] = (short)f2bf(g0.w);
            a1[4] = (short)f2bf(g1.x); a1[5] = (short)f2bf(g1.y);
            a1[6] = (short)f2bf(g1.z); a1[7] = (short)f2bf(g1.w);
        }
#pragma unroll
        for (int nb = 0; nb < 16; ++nb) {
            short8 bf = *(const short8*)(Bp + (size_t)nb * 4096 + kc * 32);
            acc0[nb] = __builtin_amdgcn_mfma_f32_16x16x32_bf16(a0, bf, acc0[nb], 0, 0, 0);
            acc1[nb] = __builtin_amdgcn_mfma_f32_16x16x32_bf16(a1, bf, acc1[nb], 0, 0, 0);
        }
    }

    int ro = lk * 4;
#pragma unroll
    for (int nb = 0; nb < 16; ++nb) {
        int gc = nb * 16 + lr;
        float bb = (EPI == 1) ? bias[gc] : 0.f;
#pragma unroll
        for (int q = 0; q < 4; ++q) {
            int g0 = row0 + ro + q;
            if (g0 < M) {
                float v = acc0[nb][q];
                if (EPI == 1) v = fmaxf(v + bb, 0.f);
                C[(size_t)g0 * 256 + gc] = f2bf(v);
            }
            int g1 = row0 + 16 + ro + q;
            if (g1 < M) {
                float v = acc1[nb][q];
                if (EPI == 1) v = fmaxf(v + bb, 0.f);
                C[(size_t)g1 * 256 + gc] = f2bf(v);
            }
        }
    }
}

template <int ASRC, int EPI>
__global__ __launch_bounds__(256) void gemm_mfma(const ushort* __restrict__ A,
                                                 const float* __restrict__ Af,
                                                 const ushort* __restrict__ Bt,
                                                 const float* __restrict__ bias,
                                                 ushort* __restrict__ C, int M) {
    gemm_body<ASRC, EPI>(blockIdx.x, threadIdx.x, A, Af, Bt, bias, C, M);
}

// ---------------- merged: gemm0 (blocks 0..GB-1) + scatter (blocks GB..) ----------------
__global__ __launch_bounds__(256) void gemsca_kernel(const float* __restrict__ Af,
                                                     const ushort* __restrict__ Bt,
                                                     ushort* __restrict__ C, int M,
                                                     const int* __restrict__ src,
                                                     const int* __restrict__ dst,
                                                     const float* __restrict__ val,
                                                     int* __restrict__ cur,
                                                     const int* __restrict__ boff,
                                                     unsigned long long* __restrict__ csr) {
    if (blockIdx.x < GB) {
        gemm_body<1, 0>(blockIdx.x, threadIdx.x, nullptr, Af, Bt, nullptr, C, M);
        return;
    }
    int e = (blockIdx.x - GB) * 256 + threadIdx.x;
    if (e < EE) {
        int d = dst[e];
        int p = atomicAdd(&cur[d], 1) + boff[d >> 8];
        unsigned long long pk = (unsigned long long)(unsigned)src[e]
                              | ((unsigned long long)(unsigned)__float_as_uint(val[e]) << 32);
        __builtin_nontemporal_store(pk, &csr[p]);
    }
}

// ---------------- pull aggregation + fused RReLU -> bf16 out ----------------
__global__ __launch_bounds__(256) void agg_csr_kernel(const ushort* __restrict__ XW,
                                                      const int2* __restrict__ csr,
                                                      const int* __restrict__ rs,
                                                      const int* __restrict__ boff,
                                                      ushort* __restrict__ out) {
    int d = blockIdx.x * 4 + (threadIdx.x >> 6);
    if (d >= NN) return;
    int l = threadIdx.x & 63;
    int h = l >> 5;          // half: 0 = even edges, 1 = odd edges
    int il = l & 31;         // feature chunk: 8 bf16 at il*8
    int beg = rs[d] + boff[d >> 8];
    int end = (d + 1 < NN) ? (rs[d + 1] + boff[(d + 1) >> 8]) : EE;
    float a0 = 0.f, a1 = 0.f, a2 = 0.f, a3 = 0.f;
    float a4 = 0.f, a5 = 0.f, a6 = 0.f, a7 = 0.f;
    int i = beg + h;
    for (; i + 14 < end; i += 16) {
        int2 e[8];
        short8 x[8];
#pragma unroll
        for (int u = 0; u < 8; ++u) e[u] = csr[i + 2 * u];
#pragma unroll
        for (int u = 0; u < 8; ++u)
            x[u] = *(const short8*)&XW[(size_t)e[u].x * D + il * 8];
#pragma unroll
        for (int u = 0; u < 8; ++u) {
            float v = __int_as_float(e[u].y);
            a0 += v * bf2f((ushort)x[u][0]);
            a1 += v * bf2f((ushort)x[u][1]);
            a2 += v * bf2f((ushort)x[u][2]);
            a3 += v * bf2f((ushort)x[u][3]);
            a4 += v * bf2f((ushort)x[u][4]);
            a5 += v * bf2f((ushort)x[u][5]);
            a6 += v * bf2f((ushort)x[u][6]);
            a7 += v * bf2f((ushort)x[u][7]);
        }
    }
    for (; i + 6 < end; i += 8) {
        int2 e[4];
        short8 x[4];
#pragma unroll
        for (int u = 0; u < 4; ++u) e[u] = csr[i + 2 * u];
#pragma unroll
        for (int u = 0; u < 4; ++u)
            x[u] = *(const short8*)&XW[(size_t)e[u].x * D + il * 8];
#pragma unroll
        for (int u = 0; u < 4; ++u) {
            float v = __int_as_float(e[u].y);
            a0 += v * bf2f((ushort)x[u][0]);
            a1 += v * bf2f((ushort)x[u][1]);
            a2 += v * bf2f((ushort)x[u][2]);
            a3 += v * bf2f((ushort)x[u][3]);
            a4 += v * bf2f((ushort)x[u][4]);
            a5 += v * bf2f((ushort)x[u][5]);
            a6 += v * bf2f((ushort)x[u][6]);
            a7 += v * bf2f((ushort)x[u][7]);
        }
    }
    for (; i < end; i += 2) {
        int2 e0 = csr[i];
        float v0 = __int_as_float(e0.y);
        short8 x0 = *(const short8*)&XW[(size_t)e0.x * D + il * 8];
        a0 += v0 * bf2f((ushort)x0[0]); a1 += v0 * bf2f((ushort)x0[1]);
        a2 += v0 * bf2f((ushort)x0[2]); a3 += v0 * bf2f((ushort)x0[3]);
        a4 += v0 * bf2f((ushort)x0[4]); a5 += v0 * bf2f((ushort)x0[5]);
        a6 += v0 * bf2f((ushort)x0[6]); a7 += v0 * bf2f((ushort)x0[7]);
    }
    a0 += __shfl_xor(a0, 32); a1 += __shfl_xor(a1, 32);
    a2 += __shfl_xor(a2, 32); a3 += __shfl_xor(a3, 32);
    a4 += __shfl_xor(a4, 32); a5 += __shfl_xor(a5, 32);
    a6 += __shfl_xor(a6, 32); a7 += __shfl_xor(a7, 32);
    if (h == 0) {
        float r[8] = {a0, a1, a2, a3, a4, a5, a6, a7};
        short8 o;
#pragma unroll
        for (int c = 0; c < 8; ++c) {
            float v = r[c];
            v = (v >= 0.f) ? v : SLOPE_F * v;
            o[c] = (short)f2bf(v);
        }
        *(short8*)&out[(size_t)d * D + il * 8] = o;
    }
}

// ---------------- final: logits = hid@W2 + b2 ; log_softmax over 16 classes ----------------
__global__ void mlp2_kernel(const ushort* __restrict__ hid, const float* __restrict__ W2,
                            const float* __restrict__ b2, float* __restrict__ out, int M) {
    int tid = threadIdx.x;
    int n = blockIdx.x * 16 + (tid >> 4);
    int c = tid & 15;
    if (n >= M) return;
    float acc = b2[c];
    const ushort* hp = hid + (size_t)n * D;
    for (int k = 0; k < D; k += 8) {
        short8 h8 = *(const short8*)(hp + k);
#pragma unroll
        for (int u = 0; u < 8; ++u)
            acc += bf2f((ushort)h8[u]) * W2[(k + u) * 16 + c];
    }
    float m = acc;
#pragma unroll
    for (int off = 1; off < 16; off <<= 1)
        m = fmaxf(m, __shfl_xor(m, off, 16));
    float ex = expf(acc - m);
    float s = ex;
#pragma unroll
    for (int off = 1; off < 16; off <<= 1)
        s += __shfl_xor(s, off, 16);
    out[(size_t)n * 16 + c] = acc - m - logf(s);
}

extern "C" void kernel_launch(void* const* d_in, const int* in_sizes, int n_in,
                              void* d_out, int out_size, void* d_ws, size_t ws_size,
                              hipStream_t stream) {
    const float* node_feats = (const float*)d_in[0];
    const float* edge_val   = (const float*)d_in[1];
    const float* l0_Wz = (const float*)d_in[2];
    const float* l0_Uz = (const float*)d_in[3];
    const float* l0_bz = (const float*)d_in[4];
    const float* l0_Wr = (const float*)d_in[5];
    const float* l0_Ur = (const float*)d_in[6];
    const float* l0_br = (const float*)d_in[7];
    const float* l0_Wh = (const float*)d_in[8];
    const float* l0_Uh = (const float*)d_in[9];
    const float* l0_bh = (const float*)d_in[10];
    const float* l0_Q0 = (const float*)d_in[11];
    const float* l1_Wz = (const float*)d_in[12];
    const float* l1_Uz = (const float*)d_in[13];
    const float* l1_bz = (const float*)d_in[14];
    const float* l1_Wr = (const float*)d_in[15];
    const float* l1_Ur = (const float*)d_in[16];
    const float* l1_br = (const float*)d_in[17];
    const float* l1_Wh = (const float*)d_in[18];
    const float* l1_Uh = (const float*)d_in[19];
    const float* l1_bh = (const float*)d_in[20];
    const float* l1_Q0 = (const float*)d_in[21];
    const float* W1 = (const float*)d_in[22];
    const float* b1 = (const float*)d_in[23];
    const float* W2 = (const float*)d_in[24];
    const float* b2 = (const float*)d_in[25];
    const int* e_src = (const int*)d_in[26];
    const int* e_dst = (const int*)d_in[27];
    float* out = (float*)d_out;

    // workspace layout
    const size_t BIG = (size_t)NN * D;   // 12.8M elements
    ushort* XWb = (ushort*)d_ws;                 // bf16 GEMM out
    ushort* H   = XWb + BIG;                     // bf16 activations (h1/h2)
    ushort* Bt  = H + BIG;                       // 3 x 65536 bf16 (Qt0, Qt1, W1T)
    ushort* RQt = Bt + 3 * 65536;                // 2 x 65536 bf16
    ushort* WB  = RQt + 2 * 65536;               // 8 mats x 2(hi/lo) x 65536 bf16
    int2*   csr = (int2*)(WB + 16 * 65536);      // EE
    int*    deg = (int*)(csr + EE);              // NN
    int*    done = deg + NN;                     // 1
    int*    bar  = done + 1;                     // 12   (memset with deg)
    int*    rs  = bar + 12;                      // NN
    int*    cur = rs + NN;                       // NN
    int*    bsum = cur + NN;                     // 200
    int*    boff = bsum + 200;                   // 200

    // --- only timestep 5 contributes to the output ---
    const float* feats5 = node_feats + (size_t)5 * BIG;
    const int*   src5   = e_src + (size_t)5 * EE;
    const int*   dst5   = e_dst + (size_t)5 * EE;
    const float* val5   = edge_val + (size_t)5 * EE;

    // zero deg + done + bar
    hipMemsetAsync(deg, 0, (NN + 13) * sizeof(int), stream);

    // --- prep (112 blocks) + histogram ---
    const int histblocks = (EE + 255) / 256;
    prephist_kernel<<<112 + histblocks, 256, 0, stream>>>(
        l0_Wz, l0_Uz, l0_Wr, l0_Ur, l0_Wh, l0_Uh,
        l1_Wz, l1_Uz, l1_Wr, l1_Ur, l1_Wh, l1_Uh,
        W1, l0_Q0, l1_Q0, WB, Bt + 2 * 65536, Bt, dst5, deg);

    // --- MFMA GRU (128 blocks, grid barriers) + hierarchical scan (196 blocks) ---
    grubar_kernel<<<128 + NCH, 256, 0, stream>>>(WB, l0_bz, l0_br, l0_bh,
                                                 l1_bz, l1_br, l1_bh,
                                                 Bt, RQt, bar,
                                                 deg, rs, cur, bsum, boff, done);

    // --- gemm0 (A = fp32 feats, B = Qt0) + scatter, one launch ---
    gemsca_kernel<<<GB + histblocks, 256, 0, stream>>>(feats5, Bt + 0 * 65536, XWb, NN,
                                                       src5, dst5, val5, cur, boff,
                                                       (unsigned long long*)csr);

    const int ablocks = (NN + 3) / 4;           // 12500

    agg_csr_kernel<<<ablocks, 256, 0, stream>>>(XWb, csr, rs, boff, H);

    gemm_mfma<0, 0><<<GB, 256, 0, stream>>>(H, nullptr, Bt + 1 * 65536, nullptr, XWb, NN);
    agg_csr_kernel<<<ablocks, 256, 0, stream>>>(XWb, csr, rs, boff, H);

    gemm_mfma<0, 1><<<GB, 256, 0, stream>>>(H, nullptr, Bt + 2 * 65536, b1, XWb, NN);
    mlp2_kernel<<<(NN + 15) / 16, 256, 0, stream>>>(XWb, W2, b2, out, NN);
}

// Round 11
// 682.907 us; speedup vs baseline: 1.2358x; 1.2358x over previous
//
#include <hip/hip_runtime.h>
#include <cstddef>

#define SLOPE_F (11.0f / 48.0f)

static const int NN = 50000;     // nodes
static const int EE = 1600000;   // edges per timestep
static const int D  = 256;
static const int NCH = 196;      // scan chunks = ceil(NN/256)
static const int GB  = 391;      // gemm blocks = ceil(NN/128)

typedef __attribute__((ext_vector_type(8))) short short8;
typedef __attribute__((ext_vector_type(4))) float f32x4;

__device__ __forceinline__ ushort f2bf(float f) {
    unsigned u = __float_as_uint(f);
    unsigned r = (u + 0x7fffu + ((u >> 16) & 1u)) >> 16;
    return (ushort)r;
}
__device__ __forceinline__ float bf2f(ushort u) {
    return __uint_as_float(((unsigned)u) << 16);
}

// ---------------- prep + dst histogram ----------------
// blocks [0,128): GRU weights transposed -> WB[mat][k][i] bf16 (mat = layer*4 + {z,r,h,u})
// blocks [128,144): BtW1[n][k] = bf16(W1[k][n])
// blocks [144, ...): histogram of dst into deg
__global__ __launch_bounds__(256) void prephist_kernel(
        const float* __restrict__ Wz0, const float* __restrict__ Uz0,
        const float* __restrict__ Wr0, const float* __restrict__ Ur0,
        const float* __restrict__ Wh0, const float* __restrict__ Uh0,
        const float* __restrict__ Wz1, const float* __restrict__ Uz1,
        const float* __restrict__ Wr1, const float* __restrict__ Ur1,
        const float* __restrict__ Wh1, const float* __restrict__ Uh1,
        const float* __restrict__ W1,
        ushort* __restrict__ WB, ushort* __restrict__ BtW1,
        const int* __restrict__ dst, int* __restrict__ deg) {
    int b = blockIdx.x;
    int tid = threadIdx.x;
    if (b >= 144) {
        int e = (b - 144) * 256 + tid;
        if (e < EE) atomicAdd(&deg[dst[e]], 1);
        return;
    }
    __shared__ float lt[64][65];
    if (b < 128) {
        int mat = b >> 4;
        int tr = (b >> 2) & 3, tc = b & 3;
        const float* P = nullptr; const float* S = nullptr;
        switch (mat) {
            case 0: P = Wz0; S = Uz0; break;
            case 1: P = Wr0; S = Ur0; break;
            case 2: P = Wh0; break;
            case 3: P = Uh0; break;
            case 4: P = Wz1; S = Uz1; break;
            case 5: P = Wr1; S = Ur1; break;
            case 6: P = Wh1; break;
            default: P = Uh1; break;
        }
#pragma unroll
        for (int r0 = 0; r0 < 64; r0 += 4) {
            int r = r0 + (tid >> 6);
            int c = tid & 63;
            int row = tr * 64 + r, col = tc * 64 + c;
            float v = P[row * 256 + col];
            if (S) v += S[row * 256 + col];
            lt[r][c] = v;
        }
        __syncthreads();
        // WB[mat][k][i] = P[i][k] : k = col, i = row
#pragma unroll
        for (int c0 = 0; c0 < 64; c0 += 4) {
            int c = c0 + (tid >> 6);
            int r = tid & 63;
            WB[(size_t)mat * 65536 + (size_t)(tc * 64 + c) * 256 + tr * 64 + r] =
                f2bf(lt[r][c]);
        }
    } else {
        int t = b - 128;
        int tr = (t >> 2) & 3, tc = t & 3;
#pragma unroll
        for (int r0 = 0; r0 < 64; r0 += 4) {
            int r = r0 + (tid >> 6);
            int c = tid & 63;
            lt[r][c] = W1[(tr * 64 + r) * 256 + tc * 64 + c];
        }
        __syncthreads();
#pragma unroll
        for (int c0 = 0; c0 < 64; c0 += 4) {
            int c = c0 + (tid >> 6);
            int r = tid & 63;
            BtW1[(size_t)(tc * 64 + c) * 256 + tr * 64 + r] = f2bf(lt[r][c]);
        }
    }
}

// ---------------- GRU: 1 column per block (512 blocks) + chunk-scan (blocks 512..707) ----
// Column j of Qn depends only on column j of Q -> blocks fully independent.
// bf16 weights (WB[k][i], coalesced across i=tid), fp32 state in LDS.
// Final Q written in GEMM B layout: Bt[layer][j][i].
__global__ __launch_bounds__(256) void gruscan_kernel(
        const ushort* __restrict__ WB,
        const float* __restrict__ bz0, const float* __restrict__ br0,
        const float* __restrict__ bh0, const float* __restrict__ Q00,
        const float* __restrict__ bz1, const float* __restrict__ br1,
        const float* __restrict__ bh1, const float* __restrict__ Q01,
        ushort* __restrict__ Bt,
        const int* __restrict__ deg, int* __restrict__ rs, int* __restrict__ cur,
        int* __restrict__ bsum, int* __restrict__ boff, int* __restrict__ done) {
    int tid = threadIdx.x;
    if (blockIdx.x >= 512) {
        // ---- chunk-local exclusive scan + last-block finisher ----
        __shared__ int wsum[4];
        __shared__ int lastflag;
        int blk = blockIdx.x - 512;          // 0..195
        int i = blk * 256 + tid;
        int lane = tid & 63, wv = tid >> 6;
        int v = (i < NN) ? deg[i] : 0;
        int x = v;
#pragma unroll
        for (int off = 1; off < 64; off <<= 1) {
            int t = __shfl_up(x, off, 64);
            if (lane >= off) x += t;
        }
        if (lane == 63) wsum[wv] = x;
        __syncthreads();
        if (tid == 0) {
            int s = 0;
#pragma unroll
            for (int q = 0; q < 4; ++q) { int t = wsum[q]; wsum[q] = s; s += t; }
            bsum[blk] = s;
        }
        __syncthreads();
        if (i < NN) { int p = wsum[wv] + x - v; rs[i] = p; cur[i] = p; }
        __threadfence();
        if (tid == 0) lastflag = (atomicAdd(done, 1) == NCH - 1);
        __syncthreads();
        if (lastflag) {
            __threadfence();
            int bv = (tid < NCH) ? bsum[tid] : 0;
            int bx = bv;
#pragma unroll
            for (int off = 1; off < 64; off <<= 1) {
                int t = __shfl_up(bx, off, 64);
                if (lane >= off) bx += t;
            }
            if (lane == 63) wsum[wv] = bx;
            __syncthreads();
            if (tid == 0) {
                int s = 0;
#pragma unroll
                for (int q = 0; q < 4; ++q) { int t = wsum[q]; wsum[q] = s; s += t; }
            }
            __syncthreads();
            if (tid < NCH) boff[tid] = wsum[wv] + bx - bv;
        }
        return;
    }
    // ---- GRU: one column j of one layer ----
    __shared__ float qs[256];
    __shared__ float rqs[256];
    int layer = blockIdx.x >> 8;
    int j = blockIdx.x & 255;
    int i = tid;
    const ushort* Mz = WB + ((size_t)layer * 4 + 0) * 65536;
    const ushort* Mr = WB + ((size_t)layer * 4 + 1) * 65536;
    const ushort* Wh = WB + ((size_t)layer * 4 + 2) * 65536;
    const ushort* Uh = WB + ((size_t)layer * 4 + 3) * 65536;
    const float* bz = layer ? bz1 : bz0;
    const float* br = layer ? br1 : br0;
    const float* bh = layer ? bh1 : bh0;
    const float* Q0 = layer ? Q01 : Q00;

    float bzv = bz[i * 256 + j];
    float brv = br[i * 256 + j];
    float bhv = bh[i * 256 + j];

    qs[i] = Q0[i * 256 + j];
    __syncthreads();

    for (int step = 0; step < 6; ++step) {
        float az = 0.f, ar = 0.f, ah = 0.f;
#pragma unroll 8
        for (int k = 0; k < 256; ++k) {
            float q = qs[k];
            az += bf2f(Mz[k * 256 + i]) * q;
            ar += bf2f(Mr[k * 256 + i]) * q;
            ah += bf2f(Wh[k * 256 + i]) * q;
        }
        float zz = 1.f / (1.f + expf(-(az + bzv)));
        float rr = 1.f / (1.f + expf(-(ar + brv)));
        float qo = qs[i];
        rqs[i] = rr * qo;
        __syncthreads();
        float bu = 0.f;
#pragma unroll 8
        for (int k = 0; k < 256; ++k)
            bu += bf2f(Uh[k * 256 + i]) * rqs[k];
        float h = tanhf(ah + bu + bhv);
        float qn = (1.f - zz) * qo + zz * h;
        qs[i] = qn;
        __syncthreads();
    }
    Bt[(size_t)layer * 65536 + (size_t)j * 256 + i] = f2bf(qs[i]);
}

// ---------------- MFMA GEMM body (no LDS; B is L1/L2-resident) ----------------
template <int ASRC, int EPI>
__device__ __forceinline__ void gemm_body(int bid, int tid,
                                          const ushort* __restrict__ A,
                                          const float* __restrict__ Af,
                                          const ushort* __restrict__ Bt,
                                          const float* __restrict__ bias,
                                          ushort* __restrict__ C, int M) {
    int w = tid >> 6, l = tid & 63;
    int lr = l & 15;
    int lk = l >> 4;
    int row0 = bid * 128 + w * 32;
    int ra = row0 + lr;      if (ra > M - 1) ra = M - 1;
    int rb = row0 + 16 + lr; if (rb > M - 1) rb = M - 1;
    const ushort* Ap0  = A  + (size_t)ra * 256 + lk * 8;
    const ushort* Ap1  = A  + (size_t)rb * 256 + lk * 8;
    const float*  Apf0 = Af + (size_t)ra * 256 + lk * 8;
    const float*  Apf1 = Af + (size_t)rb * 256 + lk * 8;
    const ushort* Bp   = Bt + (size_t)lr * 256 + lk * 8;

    f32x4 acc0[16] = {};
    f32x4 acc1[16] = {};
#pragma unroll
    for (int kc = 0; kc < 8; ++kc) {
        short8 a0, a1;
        if (ASRC == 0) {
            a0 = *(const short8*)(Ap0 + kc * 32);
            a1 = *(const short8*)(Ap1 + kc * 32);
        } else {
            float4 f0 = *(const float4*)(Apf0 + kc * 32);
            float4 f1 = *(const float4*)(Apf0 + kc * 32 + 4);
            float4 g0 = *(const float4*)(Apf1 + kc * 32);
            float4 g1 = *(const float4*)(Apf1 + kc * 32 + 4);
            a0[0] = (short)f2bf(f0.x); a0[1] = (short)f2bf(f0.y);
            a0[2] = (short)f2bf(f0.z); a0[3] = (short)f2bf(f0.w);
            a0[4] = (short)f2bf(f1.x); a0[5] = (short)f2bf(f1.y);
            a0[6] = (short)f2bf(f1.z); a0[7] = (short)f2bf(f1.w);
            a1[0] = (short)f2bf(g0.x); a1[1] = (short)f2bf(g0.y);
            a1[2] = (short)f2bf(g0.z); a1[3] = (short)f2bf(g0.w);
            a1[4] = (short)f2bf(g1.x); a1[5] = (short)f2bf(g1.y);
            a1[6] = (short)f2bf(g1.z); a1[7] = (short)f2bf(g1.w);
        }
#pragma unroll
        for (int nb = 0; nb < 16; ++nb) {
            short8 bf = *(const short8*)(Bp + (size_t)nb * 4096 + kc * 32);
            acc0[nb] = __builtin_amdgcn_mfma_f32_16x16x32_bf16(a0, bf, acc0[nb], 0, 0, 0);
            acc1[nb] = __builtin_amdgcn_mfma_f32_16x16x32_bf16(a1, bf, acc1[nb], 0, 0, 0);
        }
    }

    int ro = lk * 4;
#pragma unroll
    for (int nb = 0; nb < 16; ++nb) {
        int gc = nb * 16 + lr;
        float bb = (EPI == 1) ? bias[gc] : 0.f;
#pragma unroll
        for (int q = 0; q < 4; ++q) {
            int g0 = row0 + ro + q;
            if (g0 < M) {
                float v = acc0[nb][q];
                if (EPI == 1) v = fmaxf(v + bb, 0.f);
                C[(size_t)g0 * 256 + gc] = f2bf(v);
            }
            int g1 = row0 + 16 + ro + q;
            if (g1 < M) {
                float v = acc1[nb][q];
                if (EPI == 1) v = fmaxf(v + bb, 0.f);
                C[(size_t)g1 * 256 + gc] = f2bf(v);
            }
        }
    }
}

template <int ASRC, int EPI>
__global__ __launch_bounds__(256) void gemm_mfma(const ushort* __restrict__ A,
                                                 const float* __restrict__ Af,
                                                 const ushort* __restrict__ Bt,
                                                 const float* __restrict__ bias,
                                                 ushort* __restrict__ C, int M) {
    gemm_body<ASRC, EPI>(blockIdx.x, threadIdx.x, A, Af, Bt, bias, C, M);
}

// ---------------- merged: gemm0 (blocks 0..GB-1) + scatter (blocks GB..) ----------------
__global__ __launch_bounds__(256) void gemsca_kernel(const float* __restrict__ Af,
                                                     const ushort* __restrict__ Bt,
                                                     ushort* __restrict__ C, int M,
                                                     const int* __restrict__ src,
                                                     const int* __restrict__ dst,
                                                     const float* __restrict__ val,
                                                     int* __restrict__ cur,
                                                     const int* __restrict__ boff,
                                                     unsigned long long* __restrict__ csr) {
    if (blockIdx.x < GB) {
        gemm_body<1, 0>(blockIdx.x, threadIdx.x, nullptr, Af, Bt, nullptr, C, M);
        return;
    }
    int e = (blockIdx.x - GB) * 256 + threadIdx.x;
    if (e < EE) {
        int d = dst[e];
        int p = atomicAdd(&cur[d], 1) + boff[d >> 8];
        unsigned long long pk = (unsigned long long)(unsigned)src[e]
                              | ((unsigned long long)(unsigned)__float_as_uint(val[e]) << 32);
        __builtin_nontemporal_store(pk, &csr[p]);
    }
}

// ---------------- pull aggregation + fused RReLU -> bf16 out ----------------
__global__ __launch_bounds__(256) void agg_csr_kernel(const ushort* __restrict__ XW,
                                                      const int2* __restrict__ csr,
                                                      const int* __restrict__ rs,
                                                      const int* __restrict__ boff,
                                                      ushort* __restrict__ out) {
    int d = blockIdx.x * 4 + (threadIdx.x >> 6);
    if (d >= NN) return;
    int l = threadIdx.x & 63;
    int h = l >> 5;          // half: 0 = even edges, 1 = odd edges
    int il = l & 31;         // feature chunk: 8 bf16 at il*8
    int beg = rs[d] + boff[d >> 8];
    int end = (d + 1 < NN) ? (rs[d + 1] + boff[(d + 1) >> 8]) : EE;
    float a0 = 0.f, a1 = 0.f, a2 = 0.f, a3 = 0.f;
    float a4 = 0.f, a5 = 0.f, a6 = 0.f, a7 = 0.f;
    int i = beg + h;
    for (; i + 14 < end; i += 16) {
        int2 e[8];
        short8 x[8];
#pragma unroll
        for (int u = 0; u < 8; ++u) e[u] = csr[i + 2 * u];
#pragma unroll
        for (int u = 0; u < 8; ++u)
            x[u] = *(const short8*)&XW[(size_t)e[u].x * D + il * 8];
#pragma unroll
        for (int u = 0; u < 8; ++u) {
            float v = __int_as_float(e[u].y);
            a0 += v * bf2f((ushort)x[u][0]);
            a1 += v * bf2f((ushort)x[u][1]);
            a2 += v * bf2f((ushort)x[u][2]);
            a3 += v * bf2f((ushort)x[u][3]);
            a4 += v * bf2f((ushort)x[u][4]);
            a5 += v * bf2f((ushort)x[u][5]);
            a6 += v * bf2f((ushort)x[u][6]);
            a7 += v * bf2f((ushort)x[u][7]);
        }
    }
    for (; i + 6 < end; i += 8) {
        int2 e[4];
        short8 x[4];
#pragma unroll
        for (int u = 0; u < 4; ++u) e[u] = csr[i + 2 * u];
#pragma unroll
        for (int u = 0; u < 4; ++u)
            x[u] = *(const short8*)&XW[(size_t)e[u].x * D + il * 8];
#pragma unroll
        for (int u = 0; u < 4; ++u) {
            float v = __int_as_float(e[u].y);
            a0 += v * bf2f((ushort)x[u][0]);
            a1 += v * bf2f((ushort)x[u][1]);
            a2 += v * bf2f((ushort)x[u][2]);
            a3 += v * bf2f((ushort)x[u][3]);
            a4 += v * bf2f((ushort)x[u][4]);
            a5 += v * bf2f((ushort)x[u][5]);
            a6 += v * bf2f((ushort)x[u][6]);
            a7 += v * bf2f((ushort)x[u][7]);
        }
    }
    for (; i < end; i += 2) {
        int2 e0 = csr[i];
        float v0 = __int_as_float(e0.y);
        short8 x0 = *(const short8*)&XW[(size_t)e0.x * D + il * 8];
        a0 += v0 * bf2f((ushort)x0[0]); a1 += v0 * bf2f((ushort)x0[1]);
        a2 += v0 * bf2f((ushort)x0[2]); a3 += v0 * bf2f((ushort)x0[3]);
        a4 += v0 * bf2f((ushort)x0[4]); a5 += v0 * bf2f((ushort)x0[5]);
        a6 += v0 * bf2f((ushort)x0[6]); a7 += v0 * bf2f((ushort)x0[7]);
    }
    a0 += __shfl_xor(a0, 32); a1 += __shfl_xor(a1, 32);
    a2 += __shfl_xor(a2, 32); a3 += __shfl_xor(a3, 32);
    a4 += __shfl_xor(a4, 32); a5 += __shfl_xor(a5, 32);
    a6 += __shfl_xor(a6, 32); a7 += __shfl_xor(a7, 32);
    if (h == 0) {
        float r[8] = {a0, a1, a2, a3, a4, a5, a6, a7};
        short8 o;
#pragma unroll
        for (int c = 0; c < 8; ++c) {
            float v = r[c];
            v = (v >= 0.f) ? v : SLOPE_F * v;
            o[c] = (short)f2bf(v);
        }
        *(short8*)&out[(size_t)d * D + il * 8] = o;
    }
}

// ---------------- final: logits = hid@W2 + b2 ; log_softmax over 16 classes ----------------
__global__ void mlp2_kernel(const ushort* __restrict__ hid, const float* __restrict__ W2,
                            const float* __restrict__ b2, float* __restrict__ out, int M) {
    int tid = threadIdx.x;
    int n = blockIdx.x * 16 + (tid >> 4);
    int c = tid & 15;
    if (n >= M) return;
    float acc = b2[c];
    const ushort* hp = hid + (size_t)n * D;
    for (int k = 0; k < D; k += 8) {
        short8 h8 = *(const short8*)(hp + k);
#pragma unroll
        for (int u = 0; u < 8; ++u)
            acc += bf2f((ushort)h8[u]) * W2[(k + u) * 16 + c];
    }
    float m = acc;
#pragma unroll
    for (int off = 1; off < 16; off <<= 1)
        m = fmaxf(m, __shfl_xor(m, off, 16));
    float ex = expf(acc - m);
    float s = ex;
#pragma unroll
    for (int off = 1; off < 16; off <<= 1)
        s += __shfl_xor(s, off, 16);
    out[(size_t)n * 16 + c] = acc - m - logf(s);
}

extern "C" void kernel_launch(void* const* d_in, const int* in_sizes, int n_in,
                              void* d_out, int out_size, void* d_ws, size_t ws_size,
                              hipStream_t stream) {
    const float* node_feats = (const float*)d_in[0];
    const float* edge_val   = (const float*)d_in[1];
    const float* l0_Wz = (const float*)d_in[2];
    const float* l0_Uz = (const float*)d_in[3];
    const float* l0_bz = (const float*)d_in[4];
    const float* l0_Wr = (const float*)d_in[5];
    const float* l0_Ur = (const float*)d_in[6];
    const float* l0_br = (const float*)d_in[7];
    const float* l0_Wh = (const float*)d_in[8];
    const float* l0_Uh = (const float*)d_in[9];
    const float* l0_bh = (const float*)d_in[10];
    const float* l0_Q0 = (const float*)d_in[11];
    const float* l1_Wz = (const float*)d_in[12];
    const float* l1_Uz = (const float*)d_in[13];
    const float* l1_bz = (const float*)d_in[14];
    const float* l1_Wr = (const float*)d_in[15];
    const float* l1_Ur = (const float*)d_in[16];
    const float* l1_br = (const float*)d_in[17];
    const float* l1_Wh = (const float*)d_in[18];
    const float* l1_Uh = (const float*)d_in[19];
    const float* l1_bh = (const float*)d_in[20];
    const float* l1_Q0 = (const float*)d_in[21];
    const float* W1 = (const float*)d_in[22];
    const float* b1 = (const float*)d_in[23];
    const float* W2 = (const float*)d_in[24];
    const float* b2 = (const float*)d_in[25];
    const int* e_src = (const int*)d_in[26];
    const int* e_dst = (const int*)d_in[27];
    float* out = (float*)d_out;

    // workspace layout
    const size_t BIG = (size_t)NN * D;   // 12.8M elements
    ushort* XWb = (ushort*)d_ws;                 // bf16 GEMM out
    ushort* H   = XWb + BIG;                     // bf16 activations (h1/h2)
    ushort* Bt  = H + BIG;                       // 3 x 65536 bf16 (Qt0, Qt1, W1T)
    ushort* WB  = Bt + 3 * 65536;                // 8 mats x 65536 bf16 (transposed)
    int2*   csr = (int2*)(WB + 8 * 65536);       // EE
    int*    deg = (int*)(csr + EE);              // NN
    int*    done = deg + NN;                     // 1
    int*    rs  = done + 1;                      // NN
    int*    cur = rs + NN;                       // NN
    int*    bsum = cur + NN;                     // 200
    int*    boff = bsum + 200;                   // 200

    // --- only timestep 5 contributes to the output ---
    const float* feats5 = node_feats + (size_t)5 * BIG;
    const int*   src5   = e_src + (size_t)5 * EE;
    const int*   dst5   = e_dst + (size_t)5 * EE;
    const float* val5   = edge_val + (size_t)5 * EE;

    // zero deg + done
    hipMemsetAsync(deg, 0, (NN + 1) * sizeof(int), stream);

    // --- prep (144 blocks) + histogram ---
    const int histblocks = (EE + 255) / 256;
    prephist_kernel<<<144 + histblocks, 256, 0, stream>>>(
        l0_Wz, l0_Uz, l0_Wr, l0_Ur, l0_Wh, l0_Uh,
        l1_Wz, l1_Uz, l1_Wr, l1_Ur, l1_Wh, l1_Uh,
        W1, WB, Bt + 2 * 65536, dst5, deg);

    // --- GRU (512 blocks, 1 col each) + hierarchical scan (196 blocks) ---
    gruscan_kernel<<<512 + NCH, 256, 0, stream>>>(WB, l0_bz, l0_br, l0_bh, l0_Q0,
                                                  l1_bz, l1_br, l1_bh, l1_Q0, Bt,
                                                  deg, rs, cur, bsum, boff, done);

    // --- gemm0 (A = fp32 feats, B = Qt0) + scatter, one launch ---
    gemsca_kernel<<<GB + histblocks, 256, 0, stream>>>(feats5, Bt + 0 * 65536, XWb, NN,
                                                       src5, dst5, val5, cur, boff,
                                                       (unsigned long long*)csr);

    const int ablocks = (NN + 3) / 4;           // 12500

    agg_csr_kernel<<<ablocks, 256, 0, stream>>>(XWb, csr, rs, boff, H);

    gemm_mfma<0, 0><<<GB, 256, 0, stream>>>(H, nullptr, Bt + 1 * 65536, nullptr, XWb, NN);
    agg_csr_kernel<<<ablocks, 256, 0, stream>>>(XWb, csr, rs, boff, H);

    gemm_mfma<0, 1><<<GB, 256, 0, stream>>>(H, nullptr, Bt + 2 * 65536, b1, XWb, NN);
    mlp2_kernel<<<(NN + 15) / 16, 256, 0, stream>>>(XWb, W2, b2, out, NN);
}